// Round 11
// baseline (115.250 us; speedup 1.0000x reference)
//
#include <hip/hip_runtime.h>
#include <hip/hip_bf16.h>

#define KT 576   // CIN*9, GEMM k-order k' = (p*3+q)*64 + c

typedef __attribute__((ext_vector_type(8))) short  short8;
typedef __attribute__((ext_vector_type(4))) float  f32x4;

#define VMCNT(n) asm volatile("s_waitcnt vmcnt(" #n ")" ::: "memory")
#define SB() __builtin_amdgcn_sched_barrier(0)

__device__ __forceinline__ unsigned short f2bf(float f) {
  union { float f; unsigned int u; } v; v.f = f;
  return (unsigned short)((v.u + 0x7FFFu + ((v.u >> 16) & 1u)) >> 16);  // RNE
}

// ---------------------------------------------------------------------------
// Pre-pass: xC2 bf16, layout [hp 34][wp 34][bb 8][cs 8][bl 16][cl 8].
// ---------------------------------------------------------------------------
__global__ __launch_bounds__(256) void xC2_kernel(const float* __restrict__ x,
                                                  unsigned short* __restrict__ xC2) {
  const int hp = blockIdx.x, bb = blockIdx.y, t = threadIdx.x;
  __shared__ unsigned short tile[32 * 1024];   // [w 32][cs 8][bl 16][cl 8]
  const bool interior = (hp >= 1 && hp <= 32);
  if (interior) {
#pragma unroll 4
    for (int i = 0; i < 32; ++i) {
      const int row = i * 32 + (t >> 3);       // = bl*64 + c
      const int bl = row >> 6, c = row & 63;
      const int k = t & 7;
      const float4 v = *(const float4*)(x + ((size_t)(bb * 16 + bl) * 64 + c) * 1024 +
                                        (hp - 1) * 32 + k * 4);
      const int base = (k * 4) * 1024 + (c >> 3) * 128 + bl * 8 + (c & 7);
      tile[base]        = f2bf(v.x);
      tile[base + 1024] = f2bf(v.y);
      tile[base + 2048] = f2bf(v.z);
      tile[base + 3072] = f2bf(v.w);
    }
  }
  __syncthreads();
  unsigned short* dst = xC2 + (size_t)hp * 278528 + (size_t)bb * 1024;
  const uint4 z = make_uint4(0u, 0u, 0u, 0u);
  for (int idx = t; idx < 34 * 128; idx += 256) {
    const int wp = idx >> 7, s = idx & 127;
    uint4 v = z;
    if (interior && wp >= 1 && wp <= 32) v = *(const uint4*)&tile[(wp - 1) * 1024 + s * 8];
    *(uint4*)(dst + (size_t)wp * 8192 + s * 8) = v;
  }
}

// ---------------------------------------------------------------------------
// Main: 512 blocks = (h 32) x (wq 8) x (half 2); 2 blocks/CU resident.
// 4 chained mini-GEMMs (w = wq*4+j), M=128b x N=32d x K=576. W in 9-load
// half-batches reusing ONE wreg[9] (scatter frees regs before next issue);
// uniform VMCNT(21) ledger, >=12 loads always in flight. Coalesced tmp
// epilogue (full-line stores) + tr_out transpose.
// ---------------------------------------------------------------------------
__global__ __launch_bounds__(256, 2) void lc_main(const float* __restrict__ Wt,
                                                  const float* __restrict__ bias,
                                                  const unsigned short* __restrict__ xC2,
                                                  float* __restrict__ out,
                                                  float* __restrict__ tmp,
                                                  int useTmp) {
  __shared__ unsigned short Wl[2][32 * KT];   // 2 x 36864 B
  __shared__ float blds[128];                 // [j 4][dl 32]

  const int bid = (int)blockIdx.x;
  const int swz = (bid & 7) * 64 + (bid >> 3);    // 64-block chunks per XCD
  const int h = swz >> 4, rem = swz & 15, wq = rem >> 1, half = rem & 1;
  const int t = threadIdx.x, lane = t & 63, wv = t >> 6;
  const int l15 = lane & 15, lg = lane >> 4;

  if (t < 128)
    blds[t] = bias[(half * 32 + (t & 31)) * 1024 + h * 32 + wq * 4 + (t >> 5)];

  const unsigned short* xA = xC2 + (size_t)wv * 2048 + lg * 128 + l15 * 8;
  const int x7 = l15 & 7;
  const int wrow0 = l15 * KT;
  const int wrow1 = (16 + l15) * KT;

  f32x4 acc[4][2][2];
#pragma unroll
  for (int j = 0; j < 4; ++j)
#pragma unroll
    for (int bt = 0; bt < 2; ++bt)
#pragma unroll
      for (int dt = 0; dt < 2; ++dt) acc[j][bt][dt] = (f32x4){0.f, 0.f, 0.f, 0.f};

  short8 As0[3][3], As1[3][3];   // A slots [(j*6+g)%3][s]
  float4 wreg[9];                // ONE half-batch of W; reused A/B

#define ISSUE_W9(jj, hs)                                                      \
  {                                                                           \
    const float* ws = Wt + (size_t)(h * 32 + wq * 4 + (jj)) * (64 * KT) +     \
                      (size_t)half * (32 * KT);                               \
    _Pragma("unroll")                                                         \
    for (int i = 0; i < 9; ++i) {                                             \
      const float4* p = (const float4*)ws + (((hs) * 9 + i) * 256 + t);       \
      asm volatile("global_load_dwordx4 %0, %1, off" : "=v"(wreg[i]) : "v"(p)); \
    }                                                                         \
  }

#define ISSUE_A(K)                                                            \
  {                                                                           \
    _Pragma("unroll")                                                         \
    for (int s = 0; s < 3; ++s) {                                             \
      const int step = ((K) % 6) * 3 + s;                                     \
      const int pq = step >> 1, p = pq / 3, q = pq - p * 3;                   \
      const size_t off = (size_t)(h + p) * 278528 +                           \
                         (size_t)(wq * 4 + (K) / 6 + q) * 8192 + (step & 1) * 512; \
      const short8* p0 = (const short8*)(xA + off);                           \
      const short8* p1 = (const short8*)(xA + off + 1024);                    \
      asm volatile("global_load_dwordx4 %0, %1, off" : "=v"(As0[(K) % 3][s]) : "v"(p0)); \
      asm volatile("global_load_dwordx4 %0, %1, off" : "=v"(As1[(K) % 3][s]) : "v"(p1)); \
    }                                                                         \
  }

#define SCATTER9(buf, hs)                                                     \
  {                                                                           \
    _Pragma("unroll")                                                         \
    for (int i = 0; i < 9; ++i) {                                             \
      const int f = ((((hs) * 9) + i) * 256 + t) * 4;                         \
      const int d = (((unsigned)(f >> 6)) * 7282u) >> 16;                     \
      int kn = f - d * 576;                                                   \
      int c = ((unsigned)kn * 7282u) >> 16;                                   \
      int r = kn - c * 9;                                                     \
      const float vv[4] = {wreg[i].x, wreg[i].y, wreg[i].z, wreg[i].w};       \
      _Pragma("unroll")                                                       \
      for (int jx = 0; jx < 4; ++jx) {                                        \
        const int kp = r * 64 + c;                                            \
        const int slot = (kp >> 3) ^ (d & 7);                                 \
        Wl[buf][d * KT + slot * 8 + (kp & 7)] = f2bf(vv[jx]);                 \
        if (++r == 9) { r = 0; ++c; }                                         \
      }                                                                       \
    }                                                                         \
  }

#define STEP(jj, gg, NN)                                                      \
  {                                                                           \
    VMCNT(NN);                                                                \
    SB();                                                                     \
    _Pragma("unroll")                                                         \
    for (int s = 0; s < 3; ++s) {                                             \
      const int sb = ((gg) * 3 + s) * 4 + lg;                                 \
      const short8 b0 = *(const short8*)&Wl[(jj) & 1][wrow0 + ((sb ^ x7) << 3)]; \
      const short8 b1 = *(const short8*)&Wl[(jj) & 1][wrow1 + ((sb ^ x7) << 3)]; \
      acc[(jj)][0][0] = __builtin_amdgcn_mfma_f32_16x16x32_bf16(As0[((jj) * 6 + (gg)) % 3][s], b0, acc[(jj)][0][0], 0, 0, 0); \
      acc[(jj)][1][0] = __builtin_amdgcn_mfma_f32_16x16x32_bf16(As1[((jj) * 6 + (gg)) % 3][s], b0, acc[(jj)][1][0], 0, 0, 0); \
      acc[(jj)][0][1] = __builtin_amdgcn_mfma_f32_16x16x32_bf16(As0[((jj) * 6 + (gg)) % 3][s], b1, acc[(jj)][0][1], 0, 0, 0); \
      acc[(jj)][1][1] = __builtin_amdgcn_mfma_f32_16x16x32_bf16(As1[((jj) * 6 + (gg)) % 3][s], b1, acc[(jj)][1][1], 0, 0, 0); \
    }                                                                         \
  }

  // one j-phase, j<3 (reads buf jj&1, scatters W(jj+1) into (jj+1)&1)
#define PHASE(jj)                                                             \
  ISSUE_W9(jj + 1, 0);                                                        \
  STEP(jj, 0, 21); ISSUE_A(6 * (jj) + 3);                                     \
  STEP(jj, 1, 21); ISSUE_A(6 * (jj) + 4);                                     \
  STEP(jj, 2, 21); ISSUE_A(6 * (jj) + 5);                                     \
  VMCNT(18); SB(); SCATTER9((jj + 1) & 1, 0);                                 \
  ISSUE_W9(jj + 1, 1);                                                        \
  STEP(jj, 3, 21); ISSUE_A(6 * (jj) + 6);                                     \
  STEP(jj, 4, 21); ISSUE_A(6 * (jj) + 7);                                     \
  STEP(jj, 5, 21); ISSUE_A(6 * (jj) + 8);                                     \
  VMCNT(18); SB(); SCATTER9((jj + 1) & 1, 1);                                 \
  __syncthreads();

  // ---- prologue: W0 (two halves through the same wreg) + A(0..2) ----
  ISSUE_W9(0, 0);
  ISSUE_A(0); ISSUE_A(1); ISSUE_A(2);
  VMCNT(18); SB(); SCATTER9(0, 0);
  ISSUE_W9(0, 1);
  VMCNT(0);  SB(); SCATTER9(0, 1);   // in-order retire: waits W0b only
  __syncthreads();

  PHASE(0)
  PHASE(1)
  PHASE(2)

  // ---- j=3 (reads buf1, no W prefetch) ----
  STEP(3, 0, 12); ISSUE_A(21);
  STEP(3, 1, 12); ISSUE_A(22);
  STEP(3, 2, 12); ISSUE_A(23);
  STEP(3, 3, 12);
  STEP(3, 4, 6);
  STEP(3, 5, 0);

  // ---- epilogue ----
  if (useTmp) {
    // tmp[hw][half][dl 32][b 128]: full-line coalesced stores
#pragma unroll
    for (int j = 0; j < 4; ++j) {
      float* tb = tmp + (size_t)((h * 32 + wq * 4 + j) * 2 + half) * (32 * 128) + wv * 32;
#pragma unroll
      for (int dt = 0; dt < 2; ++dt) {
        const float bv = blds[(j << 5) + dt * 16 + l15];
#pragma unroll
        for (int bt = 0; bt < 2; ++bt) {
          f32x4 v = acc[j][bt][dt];
          v[0] += bv; v[1] += bv; v[2] += bv; v[3] += bv;
          *(f32x4*)(tb + (dt * 16 + l15) * 128 + bt * 16 + lg * 4) = v;
        }
      }
    }
  } else {
    // fallback: scattered direct stores
#pragma unroll
    for (int j = 0; j < 4; ++j) {
      const int hw = h * 32 + wq * 4 + j;
#pragma unroll
      for (int dt = 0; dt < 2; ++dt) {
        const int dg = half * 32 + dt * 16 + l15;
        const float bv = blds[(j << 5) + dt * 16 + l15];
#pragma unroll
        for (int bt = 0; bt < 2; ++bt) {
#pragma unroll
          for (int i = 0; i < 4; ++i) {
            const int b = wv * 32 + bt * 16 + lg * 4 + i;
            out[(size_t)b * 65536 + (size_t)dg * 1024 + hw] = acc[j][bt][dt][i] + bv;
          }
        }
      }
    }
  }
}

// ---------------------------------------------------------------------------
// tmp[hw][half][dl][b] -> out[b][d][hw], both sides coalesced via LDS tile.
// ---------------------------------------------------------------------------
__global__ __launch_bounds__(256) void tr_out(const float* __restrict__ tmp,
                                              float* __restrict__ out) {
  const int h = blockIdx.x;        // 0..31
  const int d = blockIdx.y;        // 0..63
  const int half = d >> 5, dl = d & 31;
  const int t = threadIdx.x;
  __shared__ float ls[32 * 132];   // [w][b+pad4]
  {
    const int w = t >> 3, bc = t & 7;
    const float* src = tmp + ((size_t)((h * 32 + w) * 2 + half) * 32 + dl) * 128 + bc * 16;
    float* dst = ls + w * 132 + bc * 16;
#pragma unroll
    for (int k = 0; k < 4; ++k) ((float4*)dst)[k] = ((const float4*)src)[k];
  }
  __syncthreads();
  {
    const int b = t >> 1, wh = t & 1;
    float4 o[4];
#pragma unroll
    for (int k = 0; k < 4; ++k)
#pragma unroll
      for (int j = 0; j < 4; ++j)
        ((float*)&o[k])[j] = ls[(wh * 16 + k * 4 + j) * 132 + b];
    float* dst = out + (size_t)b * 65536 + (size_t)d * 1024 + h * 32 + wh * 16;
#pragma unroll
    for (int k = 0; k < 4; ++k) ((float4*)dst)[k] = o[k];
  }
}

extern "C" void kernel_launch(void* const* d_in, const int* in_sizes, int n_in,
                              void* d_out, int out_size, void* d_ws, size_t ws_size,
                              hipStream_t stream) {
  const float* x    = (const float*)d_in[0];
  const float* wt   = (const float*)d_in[1];
  const float* bias = (const float*)d_in[2];
  float* out        = (float*)d_out;

  unsigned short* xC2 = (unsigned short*)d_ws;          // 18,939,904 B
  const size_t XC2_BYTES = 18939904u;
  const size_t TMP_BYTES = 33554432u;                   // 1024*2*32*128*4
  const int useTmp = (ws_size >= XC2_BYTES + TMP_BYTES) ? 1 : 0;
  float* tmp = (float*)((char*)d_ws + XC2_BYTES);

  xC2_kernel<<<dim3(34, 8), 256, 0, stream>>>(x, xC2);
  lc_main<<<512, 256, 0, stream>>>(wt, bias, xC2, out, tmp, useTmp);
  if (useTmp) tr_out<<<dim3(32, 64), 256, 0, stream>>>(tmp, out);
}

// Round 12
// 78.755 us; speedup vs baseline: 1.4634x; 1.4634x over previous
//
#include <hip/hip_runtime.h>
#include <hip/hip_bf16.h>

#define KT 576   // CIN*9, GEMM k-order k' = (p*3+q)*64 + c

typedef __attribute__((ext_vector_type(8))) short  short8;
typedef __attribute__((ext_vector_type(4))) float  f32x4;

#define VMCNT(n) asm volatile("s_waitcnt vmcnt(" #n ")" ::: "memory")
#define SB() __builtin_amdgcn_sched_barrier(0)

__device__ __forceinline__ unsigned short f2bf(float f) {
  union { float f; unsigned int u; } v; v.f = f;
  return (unsigned short)((v.u + 0x7FFFu + ((v.u >> 16) & 1u)) >> 16);  // RNE
}

// ---------------------------------------------------------------------------
// Pre-pass: xC2 bf16, layout [hp 34][wp 34][bb 8][cs 8][bl 16][cl 8].
// ---------------------------------------------------------------------------
__global__ __launch_bounds__(256) void xC2_kernel(const float* __restrict__ x,
                                                  unsigned short* __restrict__ xC2) {
  const int hp = blockIdx.x, bb = blockIdx.y, t = threadIdx.x;
  __shared__ unsigned short tile[32 * 1024];   // [w 32][cs 8][bl 16][cl 8]
  const bool interior = (hp >= 1 && hp <= 32);
  if (interior) {
#pragma unroll 4
    for (int i = 0; i < 32; ++i) {
      const int row = i * 32 + (t >> 3);       // = bl*64 + c
      const int bl = row >> 6, c = row & 63;
      const int k = t & 7;
      const float4 v = *(const float4*)(x + ((size_t)(bb * 16 + bl) * 64 + c) * 1024 +
                                        (hp - 1) * 32 + k * 4);
      const int base = (k * 4) * 1024 + (c >> 3) * 128 + bl * 8 + (c & 7);
      tile[base]        = f2bf(v.x);
      tile[base + 1024] = f2bf(v.y);
      tile[base + 2048] = f2bf(v.z);
      tile[base + 3072] = f2bf(v.w);
    }
  }
  __syncthreads();
  unsigned short* dst = xC2 + (size_t)hp * 278528 + (size_t)bb * 1024;
  const uint4 z = make_uint4(0u, 0u, 0u, 0u);
  for (int idx = t; idx < 34 * 128; idx += 256) {
    const int wp = idx >> 7, s = idx & 127;
    uint4 v = z;
    if (interior && wp >= 1 && wp <= 32) v = *(const uint4*)&tile[(wp - 1) * 1024 + s * 8];
    *(uint4*)(dst + (size_t)wp * 8192 + s * 8) = v;
  }
}

// ---------------------------------------------------------------------------
// Main: 512 blocks = (h 32) x (wq 8) x (half 2). 4 chained mini-GEMMs
// (w = wq*4+j), M=128b x N=32d x K=576. W in 9-load half-batches through ONE
// wreg[9]; uniform counted-vmcnt ledger (>=12 loads in flight). launch_bounds
// (256,1): let the allocator take ~168 arch + 64 acc = 232 <= 256 total ->
// 2 blocks/CU WITHOUT spills (the (256,2) cap at 128 caused scratch traffic).
// ---------------------------------------------------------------------------
__global__ __launch_bounds__(256, 1) void lc_main(const float* __restrict__ Wt,
                                                  const float* __restrict__ bias,
                                                  const unsigned short* __restrict__ xC2,
                                                  float* __restrict__ out,
                                                  float* __restrict__ tmp,
                                                  int useTmp) {
  __shared__ unsigned short Wl[2][32 * KT];   // 2 x 36864 B
  __shared__ float blds[128];                 // [j 4][dl 32]

  const int bid = (int)blockIdx.x;
  const int swz = (bid & 7) * 64 + (bid >> 3);    // 64-block chunks per XCD
  const int h = swz >> 4, rem = swz & 15, wq = rem >> 1, half = rem & 1;
  const int t = threadIdx.x, lane = t & 63, wv = t >> 6;
  const int l15 = lane & 15, lg = lane >> 4;

  if (t < 128)
    blds[t] = bias[(half * 32 + (t & 31)) * 1024 + h * 32 + wq * 4 + (t >> 5)];

  const unsigned short* xA = xC2 + (size_t)wv * 2048 + lg * 128 + l15 * 8;
  const int x7 = l15 & 7;
  const int wrow0 = l15 * KT;
  const int wrow1 = (16 + l15) * KT;

  f32x4 acc[4][2][2];
#pragma unroll
  for (int j = 0; j < 4; ++j)
#pragma unroll
    for (int bt = 0; bt < 2; ++bt)
#pragma unroll
      for (int dt = 0; dt < 2; ++dt) acc[j][bt][dt] = (f32x4){0.f, 0.f, 0.f, 0.f};

  short8 As0[3][3], As1[3][3];   // A slots [(j*6+g)%3][s]
  float4 wreg[9];                // ONE half-batch of W; reused

#define ISSUE_W9(jj, hs)                                                      \
  {                                                                           \
    const float* ws = Wt + (size_t)(h * 32 + wq * 4 + (jj)) * (64 * KT) +     \
                      (size_t)half * (32 * KT);                               \
    _Pragma("unroll")                                                         \
    for (int i = 0; i < 9; ++i) {                                             \
      const float4* p = (const float4*)ws + (((hs) * 9 + i) * 256 + t);       \
      asm volatile("global_load_dwordx4 %0, %1, off" : "=v"(wreg[i]) : "v"(p)); \
    }                                                                         \
  }

#define ISSUE_A(K)                                                            \
  {                                                                           \
    _Pragma("unroll")                                                         \
    for (int s = 0; s < 3; ++s) {                                             \
      const int step = ((K) % 6) * 3 + s;                                     \
      const int pq = step >> 1, p = pq / 3, q = pq - p * 3;                   \
      const size_t off = (size_t)(h + p) * 278528 +                           \
                         (size_t)(wq * 4 + (K) / 6 + q) * 8192 + (step & 1) * 512; \
      const short8* p0 = (const short8*)(xA + off);                           \
      const short8* p1 = (const short8*)(xA + off + 1024);                    \
      asm volatile("global_load_dwordx4 %0, %1, off" : "=v"(As0[(K) % 3][s]) : "v"(p0)); \
      asm volatile("global_load_dwordx4 %0, %1, off" : "=v"(As1[(K) % 3][s]) : "v"(p1)); \
    }                                                                         \
  }

#define SCATTER9(buf, hs)                                                     \
  {                                                                           \
    _Pragma("unroll")                                                         \
    for (int i = 0; i < 9; ++i) {                                             \
      const int f = ((((hs) * 9) + i) * 256 + t) * 4;                         \
      const int d = (((unsigned)(f >> 6)) * 7282u) >> 16;                     \
      int kn = f - d * 576;                                                   \
      int c = ((unsigned)kn * 7282u) >> 16;                                   \
      int r = kn - c * 9;                                                     \
      const float vv[4] = {wreg[i].x, wreg[i].y, wreg[i].z, wreg[i].w};       \
      _Pragma("unroll")                                                       \
      for (int jx = 0; jx < 4; ++jx) {                                        \
        const int kp = r * 64 + c;                                            \
        const int slot = (kp >> 3) ^ (d & 7);                                 \
        Wl[buf][d * KT + slot * 8 + (kp & 7)] = f2bf(vv[jx]);                 \
        if (++r == 9) { r = 0; ++c; }                                         \
      }                                                                       \
    }                                                                         \
  }

#define STEP(jj, gg, NN)                                                      \
  {                                                                           \
    VMCNT(NN);                                                                \
    SB();                                                                     \
    _Pragma("unroll")                                                         \
    for (int s = 0; s < 3; ++s) {                                             \
      const int sb = ((gg) * 3 + s) * 4 + lg;                                 \
      const short8 b0 = *(const short8*)&Wl[(jj) & 1][wrow0 + ((sb ^ x7) << 3)]; \
      const short8 b1 = *(const short8*)&Wl[(jj) & 1][wrow1 + ((sb ^ x7) << 3)]; \
      acc[(jj)][0][0] = __builtin_amdgcn_mfma_f32_16x16x32_bf16(As0[((jj) * 6 + (gg)) % 3][s], b0, acc[(jj)][0][0], 0, 0, 0); \
      acc[(jj)][1][0] = __builtin_amdgcn_mfma_f32_16x16x32_bf16(As1[((jj) * 6 + (gg)) % 3][s], b0, acc[(jj)][1][0], 0, 0, 0); \
      acc[(jj)][0][1] = __builtin_amdgcn_mfma_f32_16x16x32_bf16(As0[((jj) * 6 + (gg)) % 3][s], b1, acc[(jj)][0][1], 0, 0, 0); \
      acc[(jj)][1][1] = __builtin_amdgcn_mfma_f32_16x16x32_bf16(As1[((jj) * 6 + (gg)) % 3][s], b1, acc[(jj)][1][1], 0, 0, 0); \
    }                                                                         \
  }

  // one j-phase, j<3 (reads buf jj&1, scatters W(jj+1) into (jj+1)&1)
#define PHASE(jj)                                                             \
  ISSUE_W9(jj + 1, 0);                                                        \
  STEP(jj, 0, 21); ISSUE_A(6 * (jj) + 3);                                     \
  STEP(jj, 1, 21); ISSUE_A(6 * (jj) + 4);                                     \
  STEP(jj, 2, 21); ISSUE_A(6 * (jj) + 5);                                     \
  VMCNT(18); SB(); SCATTER9((jj + 1) & 1, 0);                                 \
  ISSUE_W9(jj + 1, 1);                                                        \
  STEP(jj, 3, 21); ISSUE_A(6 * (jj) + 6);                                     \
  STEP(jj, 4, 21); ISSUE_A(6 * (jj) + 7);                                     \
  STEP(jj, 5, 21); ISSUE_A(6 * (jj) + 8);                                     \
  VMCNT(18); SB(); SCATTER9((jj + 1) & 1, 1);                                 \
  __syncthreads();

  // ---- prologue: W0 (two halves through the same wreg) + A(0..2) ----
  ISSUE_W9(0, 0);
  ISSUE_A(0); ISSUE_A(1); ISSUE_A(2);
  VMCNT(18); SB(); SCATTER9(0, 0);
  ISSUE_W9(0, 1);
  VMCNT(0);  SB(); SCATTER9(0, 1);   // in-order retire: waits W0b only
  __syncthreads();

  PHASE(0)
  PHASE(1)
  PHASE(2)

  // ---- j=3 (reads buf1, no W prefetch) ----
  STEP(3, 0, 12); ISSUE_A(21);
  STEP(3, 1, 12); ISSUE_A(22);
  STEP(3, 2, 12); ISSUE_A(23);
  STEP(3, 3, 12);
  STEP(3, 4, 6);
  STEP(3, 5, 0);

  // ---- epilogue ----
  if (useTmp) {
    // tmp[hw][half][dl 32][b 128]: full-line coalesced stores
#pragma unroll
    for (int j = 0; j < 4; ++j) {
      float* tb = tmp + (size_t)((h * 32 + wq * 4 + j) * 2 + half) * (32 * 128) + wv * 32;
#pragma unroll
      for (int dt = 0; dt < 2; ++dt) {
        const float bv = blds[(j << 5) + dt * 16 + l15];
#pragma unroll
        for (int bt = 0; bt < 2; ++bt) {
          f32x4 v = acc[j][bt][dt];
          v[0] += bv; v[1] += bv; v[2] += bv; v[3] += bv;
          *(f32x4*)(tb + (dt * 16 + l15) * 128 + bt * 16 + lg * 4) = v;
        }
      }
    }
  } else {
    // fallback: scattered direct stores
#pragma unroll
    for (int j = 0; j < 4; ++j) {
      const int hw = h * 32 + wq * 4 + j;
#pragma unroll
      for (int dt = 0; dt < 2; ++dt) {
        const int dg = half * 32 + dt * 16 + l15;
        const float bv = blds[(j << 5) + dt * 16 + l15];
#pragma unroll
        for (int bt = 0; bt < 2; ++bt) {
#pragma unroll
          for (int i = 0; i < 4; ++i) {
            const int b = wv * 32 + bt * 16 + lg * 4 + i;
            out[(size_t)b * 65536 + (size_t)dg * 1024 + hw] = acc[j][bt][dt][i] + bv;
          }
        }
      }
    }
  }
}

// ---------------------------------------------------------------------------
// tmp[hw][half][dl][b] -> out[b][d][hw], both sides coalesced via LDS tile.
// ---------------------------------------------------------------------------
__global__ __launch_bounds__(256) void tr_out(const float* __restrict__ tmp,
                                              float* __restrict__ out) {
  const int h = blockIdx.x;        // 0..31
  const int d = blockIdx.y;        // 0..63
  const int half = d >> 5, dl = d & 31;
  const int t = threadIdx.x;
  __shared__ float ls[32 * 132];   // [w][b+pad4]
  {
    const int w = t >> 3, bc = t & 7;
    const float* src = tmp + ((size_t)((h * 32 + w) * 2 + half) * 32 + dl) * 128 + bc * 16;
    float* dst = ls + w * 132 + bc * 16;
#pragma unroll
    for (int k = 0; k < 4; ++k) ((float4*)dst)[k] = ((const float4*)src)[k];
  }
  __syncthreads();
  {
    const int b = t >> 1, wh = t & 1;
    float4 o[4];
#pragma unroll
    for (int k = 0; k < 4; ++k)
#pragma unroll
      for (int j = 0; j < 4; ++j)
        ((float*)&o[k])[j] = ls[(wh * 16 + k * 4 + j) * 132 + b];
    float* dst = out + (size_t)b * 65536 + (size_t)d * 1024 + h * 32 + wh * 16;
#pragma unroll
    for (int k = 0; k < 4; ++k) ((float4*)dst)[k] = o[k];
  }
}

extern "C" void kernel_launch(void* const* d_in, const int* in_sizes, int n_in,
                              void* d_out, int out_size, void* d_ws, size_t ws_size,
                              hipStream_t stream) {
  const float* x    = (const float*)d_in[0];
  const float* wt   = (const float*)d_in[1];
  const float* bias = (const float*)d_in[2];
  float* out        = (float*)d_out;

  unsigned short* xC2 = (unsigned short*)d_ws;          // 18,939,904 B
  const size_t XC2_BYTES = 18939904u;
  const size_t TMP_BYTES = 33554432u;                   // 1024*2*32*128*4
  const int useTmp = (ws_size >= XC2_BYTES + TMP_BYTES) ? 1 : 0;
  float* tmp = (float*)((char*)d_ws + XC2_BYTES);

  xC2_kernel<<<dim3(34, 8), 256, 0, stream>>>(x, xC2);
  lc_main<<<512, 256, 0, stream>>>(wt, bias, xC2, out, tmp, useTmp);
  if (useTmp) tr_out<<<dim3(32, 64), 256, 0, stream>>>(tmp, out);
}

// Round 13
// 70.370 us; speedup vs baseline: 1.6378x; 1.1191x over previous
//
#include <hip/hip_runtime.h>
#include <hip/hip_bf16.h>

#define KT 576   // CIN*9, GEMM k-order k' = (p*3+q)*64 + c

typedef __attribute__((ext_vector_type(8))) short  short8;
typedef __attribute__((ext_vector_type(4))) float  f32x4;

#define VMCNT(n) asm volatile("s_waitcnt vmcnt(" #n ")" ::: "memory")
#define SB() __builtin_amdgcn_sched_barrier(0)

__device__ __forceinline__ unsigned short f2bf(float f) {
  union { float f; unsigned int u; } v; v.f = f;
  return (unsigned short)((v.u + 0x7FFFu + ((v.u >> 16) & 1u)) >> 16);  // RNE
}

// ---------------------------------------------------------------------------
// Pre-pass: xC2 bf16, layout [hp 34][wp 34][bb 8][cs 8][bl 16][cl 8].
// ---------------------------------------------------------------------------
__global__ __launch_bounds__(256) void xC2_kernel(const float* __restrict__ x,
                                                  unsigned short* __restrict__ xC2) {
  const int hp = blockIdx.x, bb = blockIdx.y, t = threadIdx.x;
  __shared__ unsigned short tile[32 * 1024];   // [w 32][cs 8][bl 16][cl 8]
  const bool interior = (hp >= 1 && hp <= 32);
  if (interior) {
#pragma unroll 4
    for (int i = 0; i < 32; ++i) {
      const int row = i * 32 + (t >> 3);       // = bl*64 + c
      const int bl = row >> 6, c = row & 63;
      const int k = t & 7;
      const float4 v = *(const float4*)(x + ((size_t)(bb * 16 + bl) * 64 + c) * 1024 +
                                        (hp - 1) * 32 + k * 4);
      const int base = (k * 4) * 1024 + (c >> 3) * 128 + bl * 8 + (c & 7);
      tile[base]        = f2bf(v.x);
      tile[base + 1024] = f2bf(v.y);
      tile[base + 2048] = f2bf(v.z);
      tile[base + 3072] = f2bf(v.w);
    }
  }
  __syncthreads();
  unsigned short* dst = xC2 + (size_t)hp * 278528 + (size_t)bb * 1024;
  const uint4 z = make_uint4(0u, 0u, 0u, 0u);
  for (int idx = t; idx < 34 * 128; idx += 256) {
    const int wp = idx >> 7, s = idx & 127;
    uint4 v = z;
    if (interior && wp >= 1 && wp <= 32) v = *(const uint4*)&tile[(wp - 1) * 1024 + s * 8];
    *(uint4*)(dst + (size_t)wp * 8192 + s * 8) = v;
  }
}

// ---------------------------------------------------------------------------
// Main: 512 blocks = (h 32) x (wq 8) x (half 2). 4 chained mini-GEMMs
// (w = wq*4+j), M=128b x N=32d x K=576. W(j+1)'s 18 loads issued SPREAD
// (3 per step) and drained only at the scatter (VMCNT(6)) -> W bytes stay in
// the HBM queue the whole phase (R9 drained all W at mid-phase = bursty).
// Direct float4-over-w epilogue (won its A/B at this geometry).
// ---------------------------------------------------------------------------
__global__ __launch_bounds__(256, 1) void lc_main(const float* __restrict__ Wt,
                                                  const float* __restrict__ bias,
                                                  const unsigned short* __restrict__ xC2,
                                                  float* __restrict__ out) {
  __shared__ unsigned short Wl[2][32 * KT];   // 2 x 36864 B
  __shared__ float blds[128];                 // [j 4][dl 32]

  const int bid = (int)blockIdx.x;
  const int swz = (bid & 7) * 64 + (bid >> 3);    // 64-block chunks per XCD
  const int h = swz >> 4, rem = swz & 15, wq = rem >> 1, half = rem & 1;
  const int t = threadIdx.x, lane = t & 63, wv = t >> 6;
  const int l15 = lane & 15, lg = lane >> 4;

  if (t < 128)
    blds[t] = bias[(half * 32 + (t & 31)) * 1024 + h * 32 + wq * 4 + (t >> 5)];

  const unsigned short* xA = xC2 + (size_t)wv * 2048 + lg * 128 + l15 * 8;
  const int x7 = l15 & 7;
  const int wrow0 = l15 * KT;
  const int wrow1 = (16 + l15) * KT;

  f32x4 acc[4][2][2];
#pragma unroll
  for (int j = 0; j < 4; ++j)
#pragma unroll
    for (int bt = 0; bt < 2; ++bt)
#pragma unroll
      for (int dt = 0; dt < 2; ++dt) acc[j][bt][dt] = (f32x4){0.f, 0.f, 0.f, 0.f};

  short8 As0[3][3], As1[3][3];   // A slots [(j*6+g)%3][s]
  float4 wreg[18];

#define ISSUE_W18(jj)                                                         \
  {                                                                           \
    const float* ws = Wt + (size_t)(h * 32 + wq * 4 + (jj)) * (64 * KT) +     \
                      (size_t)half * (32 * KT);                               \
    _Pragma("unroll")                                                         \
    for (int i = 0; i < 18; ++i) {                                            \
      const float4* p = (const float4*)ws + (i * 256 + t);                    \
      asm volatile("global_load_dwordx4 %0, %1, off" : "=v"(wreg[i]) : "v"(p)); \
    }                                                                         \
  }

#define ISSUE_W3(jj, ck)                                                      \
  {                                                                           \
    const float* ws = Wt + (size_t)(h * 32 + wq * 4 + (jj)) * (64 * KT) +     \
                      (size_t)half * (32 * KT);                               \
    _Pragma("unroll")                                                         \
    for (int i = 0; i < 3; ++i) {                                             \
      const float4* p = (const float4*)ws + (((ck) * 3 + i) * 256 + t);       \
      asm volatile("global_load_dwordx4 %0, %1, off" : "=v"(wreg[(ck) * 3 + i]) : "v"(p)); \
    }                                                                         \
  }

#define ISSUE_A(K)                                                            \
  {                                                                           \
    _Pragma("unroll")                                                         \
    for (int s = 0; s < 3; ++s) {                                             \
      const int step = ((K) % 6) * 3 + s;                                     \
      const int pq = step >> 1, p = pq / 3, q = pq - p * 3;                   \
      const size_t off = (size_t)(h + p) * 278528 +                           \
                         (size_t)(wq * 4 + (K) / 6 + q) * 8192 + (step & 1) * 512; \
      const short8* p0 = (const short8*)(xA + off);                           \
      const short8* p1 = (const short8*)(xA + off + 1024);                    \
      asm volatile("global_load_dwordx4 %0, %1, off" : "=v"(As0[(K) % 3][s]) : "v"(p0)); \
      asm volatile("global_load_dwordx4 %0, %1, off" : "=v"(As1[(K) % 3][s]) : "v"(p1)); \
    }                                                                         \
  }

#define SCATTER(buf)                                                          \
  {                                                                           \
    _Pragma("unroll")                                                         \
    for (int i = 0; i < 18; ++i) {                                            \
      const int f = (i * 256 + t) * 4;                                        \
      const int d = (((unsigned)(f >> 6)) * 7282u) >> 16;                     \
      int kn = f - d * 576;                                                   \
      int c = ((unsigned)kn * 7282u) >> 16;                                   \
      int r = kn - c * 9;                                                     \
      const float vv[4] = {wreg[i].x, wreg[i].y, wreg[i].z, wreg[i].w};       \
      _Pragma("unroll")                                                       \
      for (int jx = 0; jx < 4; ++jx) {                                        \
        const int kp = r * 64 + c;                                            \
        const int slot = (kp >> 3) ^ (d & 7);                                 \
        Wl[buf][d * KT + slot * 8 + (kp & 7)] = f2bf(vv[jx]);                 \
        if (++r == 9) { r = 0; ++c; }                                         \
      }                                                                       \
    }                                                                         \
  }

#define MFMAS(jj, gg)                                                         \
  {                                                                           \
    _Pragma("unroll")                                                         \
    for (int s = 0; s < 3; ++s) {                                             \
      const int sb = ((gg) * 3 + s) * 4 + lg;                                 \
      const short8 b0 = *(const short8*)&Wl[(jj) & 1][wrow0 + ((sb ^ x7) << 3)]; \
      const short8 b1 = *(const short8*)&Wl[(jj) & 1][wrow1 + ((sb ^ x7) << 3)]; \
      acc[(jj)][0][0] = __builtin_amdgcn_mfma_f32_16x16x32_bf16(As0[((jj) * 6 + (gg)) % 3][s], b0, acc[(jj)][0][0], 0, 0, 0); \
      acc[(jj)][1][0] = __builtin_amdgcn_mfma_f32_16x16x32_bf16(As1[((jj) * 6 + (gg)) % 3][s], b0, acc[(jj)][1][0], 0, 0, 0); \
      acc[(jj)][0][1] = __builtin_amdgcn_mfma_f32_16x16x32_bf16(As0[((jj) * 6 + (gg)) % 3][s], b1, acc[(jj)][0][1], 0, 0, 0); \
      acc[(jj)][1][1] = __builtin_amdgcn_mfma_f32_16x16x32_bf16(As1[((jj) * 6 + (gg)) % 3][s], b1, acc[(jj)][1][1], 0, 0, 0); \
    }                                                                         \
  }

#define STEP(jj, gg, NN) { VMCNT(NN); SB(); MFMAS(jj, gg) }
#define STEPNW(jj, gg)   { SB(); MFMAS(jj, gg) }

  // ---- prologue: W0 (18) + A(0..2); VMCNT(18) = W0 drained; scatter buf0 ----
  ISSUE_W18(0);
  ISSUE_A(0); ISSUE_A(1); ISSUE_A(2);
  VMCNT(18); SB();
  SCATTER(0);
  __syncthreads(); SB();

  // ---- phase j=0 (A0..2 possibly in flight -> waits 12/15/18) ----
  STEP(0, 0, 12); ISSUE_A(3); ISSUE_W3(1, 0);
  STEP(0, 1, 15); ISSUE_A(4); ISSUE_W3(1, 1);
  STEP(0, 2, 18); ISSUE_A(5); ISSUE_W3(1, 2);
  STEP(0, 3, 21); ISSUE_W3(1, 3); ISSUE_A(6);
  STEP(0, 4, 21); ISSUE_W3(1, 4); ISSUE_A(7);
  STEP(0, 5, 21); ISSUE_W3(1, 5); ISSUE_A(8);
  VMCNT(6); SB(); SCATTER(1);
  __syncthreads(); SB();

  // ---- phase j=1 (steady: s0/s1 pre-drained by prev VMCNT(6)) ----
  STEPNW(1, 0);   ISSUE_A(9);  ISSUE_W3(2, 0);
  STEPNW(1, 1);   ISSUE_A(10); ISSUE_W3(2, 1);
  STEP(1, 2, 18); ISSUE_A(11); ISSUE_W3(2, 2);
  STEP(1, 3, 21); ISSUE_W3(2, 3); ISSUE_A(12);
  STEP(1, 4, 21); ISSUE_W3(2, 4); ISSUE_A(13);
  STEP(1, 5, 21); ISSUE_W3(2, 5); ISSUE_A(14);
  VMCNT(6); SB(); SCATTER(0);
  __syncthreads(); SB();

  // ---- phase j=2 ----
  STEPNW(2, 0);   ISSUE_A(15); ISSUE_W3(3, 0);
  STEPNW(2, 1);   ISSUE_A(16); ISSUE_W3(3, 1);
  STEP(2, 2, 18); ISSUE_A(17); ISSUE_W3(3, 2);
  STEP(2, 3, 21); ISSUE_W3(3, 3); ISSUE_A(18);
  STEP(2, 4, 21); ISSUE_W3(3, 4); ISSUE_A(19);
  STEP(2, 5, 21); ISSUE_W3(3, 5); ISSUE_A(20);
  VMCNT(6); SB(); SCATTER(1);
  __syncthreads(); SB();

  // ---- phase j=3 (no W prefetch) ----
  STEPNW(3, 0);   ISSUE_A(21);
  STEPNW(3, 1);   ISSUE_A(22);
  STEP(3, 2, 12); ISSUE_A(23);
  STEP(3, 3, 12);
  STEP(3, 4, 6);
  STEP(3, 5, 0);

  // ---- epilogue: float4 over the 4 consecutive w (L2-merged at this geom) ----
#pragma unroll
  for (int dt = 0; dt < 2; ++dt) {
    const int dd = dt * 16 + l15;
    const int dg = half * 32 + dd;
    const float bv0 = blds[dd], bv1 = blds[32 + dd], bv2 = blds[64 + dd], bv3 = blds[96 + dd];
#pragma unroll
    for (int bt = 0; bt < 2; ++bt) {
#pragma unroll
      for (int i = 0; i < 4; ++i) {
        const int b = wv * 32 + bt * 16 + lg * 4 + i;
        float4 v;
        v.x = acc[0][bt][dt][i] + bv0;
        v.y = acc[1][bt][dt][i] + bv1;
        v.z = acc[2][bt][dt][i] + bv2;
        v.w = acc[3][bt][dt][i] + bv3;
        *(float4*)(out + (size_t)b * 65536 + (size_t)dg * 1024 + h * 32 + wq * 4) = v;
      }
    }
  }
}

extern "C" void kernel_launch(void* const* d_in, const int* in_sizes, int n_in,
                              void* d_out, int out_size, void* d_ws, size_t ws_size,
                              hipStream_t stream) {
  const float* x    = (const float*)d_in[0];
  const float* wt   = (const float*)d_in[1];
  const float* bias = (const float*)d_in[2];
  float* out        = (float*)d_out;
  unsigned short* xC2 = (unsigned short*)d_ws;   // 18,939,904 B

  xC2_kernel<<<dim3(34, 8), 256, 0, stream>>>(x, xC2);
  lc_main<<<512, 256, 0, stream>>>(wt, bias, xC2, out);
}